// Round 6
// baseline (941.869 us; speedup 1.0000x reference)
//
#include <hip/hip_runtime.h>
#include <hip/hip_bf16.h>

// DimeNet-like GNN, f32 in/out (flag=1 confirmed). Round 5: same algorithm as
// round 4 (algebraic decomposition of concat-MLPs into node-level GEMMs +
// register-accumulated segment sums over j/dst-sorted orders), hardened:
//  - no 1024-thread blocks (scan is 256-thread, two-pass)
//  - k_lin KS is a template parameter (no runtime LDS bounds)
//  - sorted/unsorted sum kernels separated; sorted loops clamp order[] values
//  - k_scatter clamps positions
// Any sort-logic bug now produces wrong numbers (absmax signal), not a fault.

#define N_NODES 16000
#define N_EDGES 256000
#define N_TRI   640000
#define N_B     128
#define OUT_DIM 32
#define L_LAYERS 3

typedef __hip_bfloat16 bf16;
typedef short s8v __attribute__((ext_vector_type(8)));
typedef float f4v __attribute__((ext_vector_type(4)));

__device__ __forceinline__ float ldx(const void* p, size_t i, int f) {
    if (f) return ((const float*)p)[i];
    return __bfloat162float(((const bf16*)p)[i]);
}

// ---- bf16 split helpers (bit-level, RNE) ----
__device__ __forceinline__ unsigned short f2bf_rne(float x) {
    unsigned int u = __float_as_uint(x);
    unsigned int r = (u + 0x7FFFu + ((u >> 16) & 1u)) >> 16;
    return (unsigned short)r;
}
__device__ __forceinline__ float bf2f(unsigned short b) {
    return __uint_as_float(((unsigned int)b) << 16);
}
__device__ __forceinline__ void split2(float a, unsigned short& h, unsigned short& l) {
    h = f2bf_rne(a);
    l = f2bf_rne(a - bf2f(h));
}
__device__ __forceinline__ void make_afrag(const float* av, s8v& ah, s8v& al) {
    #pragma unroll
    for (int j = 0; j < 8; j++) {
        unsigned short h, l; split2(av[j], h, l);
        ah[j] = (short)h; al[j] = (short)l;
    }
}

#define MFMA_STEP(ks, ah, al)                                                    \
    {                                                                            \
        _Pragma("unroll")                                                        \
        for (int nt = 0; nt < 4; nt++) {                                         \
            s8v bh = *(const s8v*)&sBhi[((ks) * 4 + nt) * 512 + lane * 8];       \
            s8v bl = *(const s8v*)&sBlo[((ks) * 4 + nt) * 512 + lane * 8];       \
            acc[nt] = __builtin_amdgcn_mfma_f32_16x16x32_bf16(ah, bh, acc[nt], 0, 0, 0); \
            acc[nt] = __builtin_amdgcn_mfma_f32_16x16x32_bf16(al, bh, acc[nt], 0, 0, 0); \
            acc[nt] = __builtin_amdgcn_mfma_f32_16x16x32_bf16(ah, bl, acc[nt], 0, 0, 0); \
        }                                                                        \
    }

#define LOAD_A8(base, ks, av)                                                    \
    {                                                                            \
        const float4* p_ = (const float4*)((base) + (ks) * 32 + quad * 8);       \
        float4 x0_ = p_[0], x1_ = p_[1];                                         \
        av[0] = x0_.x; av[1] = x0_.y; av[2] = x0_.z; av[3] = x0_.w;              \
        av[4] = x1_.x; av[5] = x1_.y; av[6] = x1_.z; av[7] = x1_.w;              \
    }

// ---------------------------------------------------------------- misc
__global__ void k_probe(const void* __restrict__ rbf, int* __restrict__ flag) {
    if (threadIdx.x == 0 && blockIdx.x == 0) {
        const float* p = (const float*)rbf;
        int good = 0;
        for (int i = 0; i < 256; i++) {
            float v = fabsf(p[i]);
            if (v > 1e-4f && v < 100.0f) good++;
        }
        *flag = (good > 192) ? 1 : 0;
    }
}

__global__ void k_fill(void* __restrict__ out, const int* __restrict__ flag,
                       float val, int n) {
    int i = blockIdx.x * blockDim.x + threadIdx.x;
    if (i < n) {
        if (*flag) ((float*)out)[i] = val;
        else       ((bf16*)out)[i] = __float2bfloat16(val);
    }
}

__global__ void k_zero(float* __restrict__ p, int n) {
    int i = blockIdx.x * blockDim.x + threadIdx.x;
    int stride = gridDim.x * blockDim.x;
    for (; i < n; i += stride) p[i] = 0.0f;
}

__global__ void k_zeroi(int* __restrict__ p, int n) {
    int i = blockIdx.x * blockDim.x + threadIdx.x;
    int stride = gridDim.x * blockDim.x;
    for (; i < n; i += stride) p[i] = 0;
}

__global__ void k_hinit(const void* __restrict__ x, float* __restrict__ h,
                        const int* __restrict__ flag) {
    int f = *flag;
    int i = blockIdx.x * blockDim.x + threadIdx.x;
    if (i < N_NODES * 64) h[i] = ldx(x, i, f);
}

// ---------------------------------------------------------------- counting sort
__global__ void k_hist(const int* __restrict__ key, int n, int* __restrict__ cnt) {
    int i = blockIdx.x * blockDim.x + threadIdx.x;
    if (i < n) {
        unsigned k = (unsigned)key[i];
        if (k < N_NODES) atomicAdd(&cnt[k], 1);
    }
}

// exclusive prefix scan of N_NODES ints, in place; 256 threads, two passes.
__global__ __launch_bounds__(256) void k_scan16k(int* __restrict__ cnt) {
    __shared__ int part[256];
    int tid = threadIdx.x;
    const int PER = (N_NODES + 255) / 256;  // 63
    int base = tid * PER;
    int s = 0;
    for (int i = 0; i < PER; i++) {
        int idx = base + i;
        if (idx < N_NODES) s += cnt[idx];
    }
    part[tid] = s;
    __syncthreads();
    for (int d = 1; d < 256; d <<= 1) {
        int v = (tid >= d) ? part[tid - d] : 0;
        __syncthreads();
        part[tid] += v;
        __syncthreads();
    }
    int run = (tid > 0) ? part[tid - 1] : 0;
    for (int i = 0; i < PER; i++) {
        int idx = base + i;
        if (idx < N_NODES) {
            int v = cnt[idx];
            cnt[idx] = run;
            run += v;
        }
    }
}

__global__ void k_scatter(const int* __restrict__ key, int n,
                          int* __restrict__ cursor, int* __restrict__ order) {
    int i = blockIdx.x * blockDim.x + threadIdx.x;
    if (i < n) {
        unsigned k = (unsigned)key[i];
        if (k < N_NODES) {
            int pos = atomicAdd(&cursor[k], 1);
            if ((unsigned)pos < (unsigned)n) order[pos] = i;  // clamped
        }
    }
}

// ---------------------------------------------------------------- generic linear
// out[n] = (relu?)(A1[n]@W[0:64] (+ A2[n]@W[64:128] if KS==4) + bias).
// Split-bf16 3-product MFMA. In-place safe (out==A1): each wave reads its 16
// rows fully into acc before storing those same 16 rows.
template<int KS>
__global__ __launch_bounds__(256) void k_lin(
    const float* __restrict__ A1, const float* __restrict__ A2,
    const void* __restrict__ W, size_t offW,
    const void* __restrict__ bias, size_t offB, int do_relu,
    const int* __restrict__ flag, float* __restrict__ out) {
    __shared__ unsigned short sBhi[KS * 2048], sBlo[KS * 2048];
    __shared__ float sBias[64];
    int f = *flag;
    for (int idx = threadIdx.x; idx < KS * 2048; idx += 256) {
        int jj = idx & 7, ln = (idx >> 3) & 63, nt = (idx >> 9) & 3, ks = idx >> 11;
        int k = ks * 32 + (ln >> 4) * 8 + jj;
        int n = nt * 16 + (ln & 15);
        float w = ldx(W, offW + (size_t)k * 64 + n, f);
        unsigned short h_, l_; split2(w, h_, l_);
        sBhi[idx] = h_; sBlo[idx] = l_;
    }
    if (threadIdx.x < 64)
        sBias[threadIdx.x] = bias ? ldx(bias, offB + threadIdx.x, f) : 0.f;
    __syncthreads();
    int lane = threadIdx.x & 63;
    int quad = lane >> 4;
    int m = lane & 15;
    int wave = blockIdx.x * 4 + (threadIdx.x >> 6);
    int nwaves = gridDim.x * 4;
    const int NT = N_NODES / 16;
    for (int tile = wave; tile < NT; tile += nwaves) {
        int row = tile * 16 + m;
        f4v acc[4];
        #pragma unroll
        for (int nt = 0; nt < 4; nt++) {
            float b = sBias[nt * 16 + m];
            acc[nt] = (f4v){b, b, b, b};
        }
        const float* r1 = A1 + (size_t)row * 64;
        float av[8]; s8v ah, al;
        LOAD_A8(r1, 0, av) make_afrag(av, ah, al); MFMA_STEP(0, ah, al)
        LOAD_A8(r1, 1, av) make_afrag(av, ah, al); MFMA_STEP(1, ah, al)
        if (KS == 4) {
            const float* r2 = A2 + (size_t)row * 64;
            LOAD_A8(r2, 0, av) make_afrag(av, ah, al); MFMA_STEP(2, ah, al)
            LOAD_A8(r2, 1, av) make_afrag(av, ah, al); MFMA_STEP(3, ah, al)
        }
        #pragma unroll
        for (int r = 0; r < 4; r++) {
            float* dp = out + (size_t)(tile * 16 + quad * 4 + r) * 64 + m;
            #pragma unroll
            for (int nt = 0; nt < 4; nt++) {
                float v = acc[nt][r];
                dp[nt * 16] = do_relu ? fmaxf(v, 0.f) : v;
            }
        }
    }
}

// ---------------------------------------------------------------- triplet segment sums
// agg_e[j] += relu(Hh[k_t] + rbf[j]@W1r + cbf[t]@W1c)
__global__ __launch_bounds__(256) void k_tri_sum_s(
    const int* __restrict__ order,
    const int* __restrict__ j_idx, const int* __restrict__ k_idx,
    const float* __restrict__ Hh, const void* __restrict__ rbf,
    const void* __restrict__ cbf, const void* __restrict__ W1, size_t offW,
    const int* __restrict__ flag, float* __restrict__ agg_e) {
    int f = *flag;
    int c = threadIdx.x & 63;
    float wr[6], wc[6];
    #pragma unroll
    for (int q = 0; q < 6; q++) {
        wr[q] = ldx(W1, offW + (size_t)(64 + q) * 64 + c, f);
        wc[q] = ldx(W1, offW + (size_t)(70 + q) * 64 + c, f);
    }
    int wave = blockIdx.x * 4 + (threadIdx.x >> 6);
    int nw = gridDim.x * 4;
    int chunk = (N_TRI + nw - 1) / nw;
    int p0 = wave * chunk;
    int p1 = p0 + chunk; if (p1 > N_TRI) p1 = N_TRI;
    if (p0 >= p1) return;
    float s = 0.f, rb = 0.f;
    int jprev = -1;
    for (int p = p0; p < p1; p++) {
        unsigned t = (unsigned)order[p];
        if (t >= N_TRI) continue;  // clamp: poison -> skip (absmax signal, no fault)
        unsigned j = (unsigned)j_idx[t];
        if (j >= N_NODES) continue;
        unsigned k = (unsigned)k_idx[t]; if (k >= N_NODES) k = 0;
        if ((int)j != jprev) {
            if (jprev >= 0) atomicAdd(&agg_e[(size_t)jprev * 64 + c], s);
            s = 0.f; jprev = (int)j;
            rb = 0.f;
            #pragma unroll
            for (int q = 0; q < 6; q++)
                rb += ldx(rbf, (size_t)j * 6 + q, f) * wr[q];
        }
        float v = Hh[(size_t)k * 64 + c] + rb;
        #pragma unroll
        for (int q = 0; q < 6; q++)
            v += ldx(cbf, (size_t)t * 6 + q, f) * wc[q];
        s += fmaxf(v, 0.f);
    }
    if (jprev >= 0) atomicAdd(&agg_e[(size_t)jprev * 64 + c], s);
}

__global__ __launch_bounds__(256) void k_tri_sum_u(
    const int* __restrict__ j_idx, const int* __restrict__ k_idx,
    const float* __restrict__ Hh, const void* __restrict__ rbf,
    const void* __restrict__ cbf, const void* __restrict__ W1, size_t offW,
    const int* __restrict__ flag, float* __restrict__ agg_e) {
    int f = *flag;
    int c = threadIdx.x & 63;
    float wr[6], wc[6];
    #pragma unroll
    for (int q = 0; q < 6; q++) {
        wr[q] = ldx(W1, offW + (size_t)(64 + q) * 64 + c, f);
        wc[q] = ldx(W1, offW + (size_t)(70 + q) * 64 + c, f);
    }
    int wave = blockIdx.x * 4 + (threadIdx.x >> 6);
    int nw = gridDim.x * 4;
    for (int t = wave; t < N_TRI; t += nw) {
        unsigned j = (unsigned)j_idx[t];
        if (j >= N_NODES) continue;
        unsigned k = (unsigned)k_idx[t]; if (k >= N_NODES) k = 0;
        float v = Hh[(size_t)k * 64 + c];
        #pragma unroll
        for (int q = 0; q < 6; q++)
            v += ldx(rbf, (size_t)j * 6 + q, f) * wr[q]
               + ldx(cbf, (size_t)t * 6 + q, f) * wc[q];
        atomicAdd(&agg_e[(size_t)j * 64 + c], fmaxf(v, 0.f));
    }
}

// ---------------------------------------------------------------- edge segment sums
// aggr[dst] += relu(Hs[src] + Ad[dst])
__global__ __launch_bounds__(256) void k_edge_sum_s(
    const int* __restrict__ order, const int* __restrict__ edge_index,
    const float* __restrict__ Hs, const float* __restrict__ Ad,
    float* __restrict__ aggr) {
    int c = threadIdx.x & 63;
    int wave = blockIdx.x * 4 + (threadIdx.x >> 6);
    int nw = gridDim.x * 4;
    int chunk = (N_EDGES + nw - 1) / nw;
    int p0 = wave * chunk;
    int p1 = p0 + chunk; if (p1 > N_EDGES) p1 = N_EDGES;
    if (p0 >= p1) return;
    float s = 0.f, ad = 0.f;
    int dprev = -1;
    for (int p = p0; p < p1; p++) {
        unsigned e = (unsigned)order[p];
        if (e >= N_EDGES) continue;  // clamp
        unsigned src = (unsigned)edge_index[e];
        unsigned dst = (unsigned)edge_index[N_EDGES + e];
        if (dst >= N_NODES) continue;
        if (src >= N_NODES) src = 0;
        if ((int)dst != dprev) {
            if (dprev >= 0) atomicAdd(&aggr[(size_t)dprev * 64 + c], s);
            s = 0.f; dprev = (int)dst;
            ad = Ad[(size_t)dst * 64 + c];
        }
        s += fmaxf(Hs[(size_t)src * 64 + c] + ad, 0.f);
    }
    if (dprev >= 0) atomicAdd(&aggr[(size_t)dprev * 64 + c], s);
}

__global__ __launch_bounds__(256) void k_edge_sum_u(
    const int* __restrict__ edge_index,
    const float* __restrict__ Hs, const float* __restrict__ Ad,
    float* __restrict__ aggr) {
    int c = threadIdx.x & 63;
    int wave = blockIdx.x * 4 + (threadIdx.x >> 6);
    int nw = gridDim.x * 4;
    for (int e = wave; e < N_EDGES; e += nw) {
        unsigned src = (unsigned)edge_index[e];
        unsigned dst = (unsigned)edge_index[N_EDGES + e];
        if (dst >= N_NODES) continue;
        if (src >= N_NODES) src = 0;
        float v = fmaxf(Hs[(size_t)src * 64 + c] + Ad[(size_t)dst * 64 + c], 0.f);
        atomicAdd(&aggr[(size_t)dst * 64 + c], v);
    }
}

// ---------------------------------------------------------------- global mean pool
__global__ void k_pool(const float* __restrict__ h, const int* __restrict__ batch,
                       float* __restrict__ pooled, float* __restrict__ cnt) {
    int lane = threadIdx.x & 63;
    int gwave = blockIdx.x * (blockDim.x >> 6) + (threadIdx.x >> 6);
    int nwaves = gridDim.x * (blockDim.x >> 6);
    for (int n = gwave; n < N_NODES; n += nwaves) {
        unsigned b = (unsigned)batch[n];
        if (b >= N_B) continue;
        atomicAdd(&pooled[b * 64 + lane], h[n * 64 + lane]);
        if (lane == 0) atomicAdd(&cnt[b], 1.0f);
    }
}

// ---------------------------------------------------------------- output head
__global__ void k_head(const float* __restrict__ pooled, const float* __restrict__ cnt,
                       const void* __restrict__ Wo1, const void* __restrict__ bo1,
                       const void* __restrict__ Wo2, const void* __restrict__ bo2,
                       const int* __restrict__ flag, void* __restrict__ out) {
    int f = *flag;
    int lane = threadIdx.x & 63;
    int b = blockIdx.x * (blockDim.x >> 6) + (threadIdx.x >> 6);
    if (b >= N_B) return;
    float c = cnt[b];
    float p = fmaxf(pooled[b * 64 + lane] / fmaxf(c, 1.0f), 0.f);
    float acc = ldx(bo1, lane, f);
    #pragma unroll
    for (int kk = 0; kk < 64; kk++)
        acc += __shfl(p, kk) * ldx(Wo1, kk * 64 + lane, f);
    float t1 = fmaxf(acc, 0.f);
    float acc2 = (lane < OUT_DIM) ? ldx(bo2, lane, f) : 0.f;
    #pragma unroll
    for (int kk = 0; kk < 64; kk++) {
        float w = (lane < OUT_DIM) ? ldx(Wo2, kk * OUT_DIM + lane, f) : 0.f;
        acc2 += __shfl(t1, kk) * w;
    }
    if (lane < OUT_DIM) {
        if (f) ((float*)out)[b * OUT_DIM + lane] = acc2;
        else   ((bf16*)out)[b * OUT_DIM + lane] = __float2bfloat16(acc2);
    }
}

extern "C" void kernel_launch(void* const* d_in, const int* in_sizes, int n_in,
                              void* d_out, int out_size, void* d_ws, size_t ws_size,
                              hipStream_t stream) {
    const int expect[19] = {
        N_NODES * 64, N_EDGES * 6, N_TRI * 6,
        L_LAYERS * 76 * 64, L_LAYERS * 64,
        L_LAYERS * 128 * 64, L_LAYERS * 64,
        L_LAYERS * 128 * 64, L_LAYERS * 64,
        L_LAYERS * 64 * 64, L_LAYERS * 64,
        64 * 64, 64, 64 * OUT_DIM, OUT_DIM,
        2 * N_EDGES, N_TRI, N_TRI, N_NODES
    };

    char* ws = (char*)d_ws;
    float* h      = (float*)(ws + 0);           // 4,096,000
    float* agg_e  = (float*)(ws + 4096000);     // 4,096,000 (agg_e, then Ad in place)
    float* aggr   = (float*)(ws + 8192000);     // 4,096,000
    float* X      = (float*)(ws + 12288000);    // 4,096,000 (Hh -> Hs -> Zn)
    float* pooled = (float*)(ws + 16384000);    // 32,768
    float* cnt    = (float*)(ws + 16416768);    // 512
    int*   flag   = (int*)(ws + 16417280);      // 256
    int*   tri_o  = (int*)(ws + 16417536);      // 2,560,000
    int*   edge_o = (int*)(ws + 18977536);      // 1,024,000
    int*   cur_t  = (int*)(ws + 20001536);      // 64,000
    int*   cur_e  = (int*)(ws + 20065536);      // 64,000
    const size_t FULL_NEED = 20129536u;
    const size_t BASE_NEED = 16417540u;

    const int out_n = N_B * OUT_DIM;

    int perm[19];
    bool used[64];
    for (int i = 0; i < 64; i++) used[i] = false;
    int fail_slot = -1;
    for (int i = 0; i < 19; i++) {
        perm[i] = -1;
        for (int jj = 0; jj < n_in && jj < 64; jj++) {
            if (!used[jj] && in_sizes[jj] == expect[i]) { used[jj] = true; perm[i] = jj; break; }
        }
        if (perm[i] < 0 && fail_slot < 0) fail_slot = i;
    }

    if (n_in < 19 || fail_slot >= 0 || ws_size < BASE_NEED) {
        float code = (ws_size < BASE_NEED) ? 40000.0f
                   : (n_in < 19)           ? 50000.0f
                   : 20000.0f + 1000.0f * (float)fail_slot;
        k_probe<<<1, 64, 0, stream>>>(d_in[0], flag);
        k_fill<<<(out_n + 255) / 256, 256, 0, stream>>>(d_out, flag, code, out_n);
        return;
    }

    const void* x    = d_in[perm[0]];
    const void* rbf  = d_in[perm[1]];
    const void* cbf  = d_in[perm[2]];
    const void* W1   = d_in[perm[3]];
    const void* b1   = d_in[perm[4]];
    const void* W2   = d_in[perm[5]];
    const void* b2   = d_in[perm[6]];
    const void* Wn1  = d_in[perm[7]];
    const void* bn1  = d_in[perm[8]];
    const void* Wn2  = d_in[perm[9]];
    const void* bn2  = d_in[perm[10]];
    const void* Wo1  = d_in[perm[11]];
    const void* bo1  = d_in[perm[12]];
    const void* Wo2  = d_in[perm[13]];
    const void* bo2  = d_in[perm[14]];
    const int* edge_index = (const int*)d_in[perm[15]];
    const int* k_idx = (const int*)d_in[perm[16]];
    const int* j_idx = (const int*)d_in[perm[17]];
    const int* batch = (const int*)d_in[perm[18]];

    const int sorted = (ws_size >= FULL_NEED) ? 1 : 0;

    k_probe<<<1, 64, 0, stream>>>(rbf, flag);
    k_zero<<<64, 256, 0, stream>>>(pooled, N_B * 64 + N_B);
    k_hinit<<<(N_NODES * 64 + 255) / 256, 256, 0, stream>>>(x, h, flag);

    if (sorted) {
        k_zeroi<<<63, 256, 0, stream>>>(cur_t, N_NODES);
        k_zeroi<<<63, 256, 0, stream>>>(cur_e, N_NODES);
        k_hist<<<(N_TRI + 255) / 256, 256, 0, stream>>>(j_idx, N_TRI, cur_t);
        k_hist<<<(N_EDGES + 255) / 256, 256, 0, stream>>>(edge_index + N_EDGES, N_EDGES, cur_e);
        k_scan16k<<<1, 256, 0, stream>>>(cur_t);
        k_scan16k<<<1, 256, 0, stream>>>(cur_e);
        k_scatter<<<(N_TRI + 255) / 256, 256, 0, stream>>>(j_idx, N_TRI, cur_t, tri_o);
        k_scatter<<<(N_EDGES + 255) / 256, 256, 0, stream>>>(edge_index + N_EDGES, N_EDGES, cur_e, edge_o);
    }

    for (int l = 0; l < L_LAYERS; l++) {
        size_t offW1  = (size_t)l * 76 * 64;
        size_t offW2  = (size_t)l * 128 * 64;
        size_t offWn2 = (size_t)l * 64 * 64;
        size_t offB   = (size_t)l * 64;
        k_zero<<<2048, 256, 0, stream>>>(agg_e, 2 * N_NODES * 64);  // agg_e+aggr
        // Hh = h @ W1[0:64] + b1
        k_lin<2><<<250, 256, 0, stream>>>(h, nullptr, W1, offW1, b1, offB, 0, flag, X);
        // agg_e += segment_sum_j relu(Hh[k] + rbf[j]@W1r + cbf[t]@W1c)
        if (sorted)
            k_tri_sum_s<<<2048, 256, 0, stream>>>(tri_o, j_idx, k_idx, X, rbf, cbf,
                                                  W1, offW1, flag, agg_e);
        else
            k_tri_sum_u<<<2048, 256, 0, stream>>>(j_idx, k_idx, X, rbf, cbf,
                                                  W1, offW1, flag, agg_e);
        // Hs = h @ W2[0:64] + b2
        k_lin<2><<<250, 256, 0, stream>>>(h, nullptr, W2, offW2, b2, offB, 0, flag, X);
        // Ad = agg_e @ W2[64:128]  (in place)
        k_lin<2><<<250, 256, 0, stream>>>(agg_e, nullptr, W2, offW2 + 64 * 64,
                                          nullptr, 0, 0, flag, agg_e);
        // aggr += segment_sum_dst relu(Hs[src] + Ad[dst])
        if (sorted)
            k_edge_sum_s<<<1024, 256, 0, stream>>>(edge_o, edge_index, X, agg_e, aggr);
        else
            k_edge_sum_u<<<1024, 256, 0, stream>>>(edge_index, X, agg_e, aggr);
        // Zn = relu([h | aggr] @ Wn1 + bn1)
        k_lin<4><<<250, 256, 0, stream>>>(h, aggr, Wn1, offW2, bn1, offB, 1, flag, X);
        // h = Zn @ Wn2 + bn2
        k_lin<2><<<250, 256, 0, stream>>>(X, nullptr, Wn2, offWn2, bn2, offB, 0, flag, h);
    }
    k_pool<<<512, 256, 0, stream>>>(h, batch, pooled, cnt);
    k_head<<<32, 256, 0, stream>>>(pooled, cnt, Wo1, bo1, Wo2, bo2, flag, d_out);
}

// Round 7
// 480.099 us; speedup vs baseline: 1.9618x; 1.9618x over previous
//
#include <hip/hip_runtime.h>
#include <hip/hip_bf16.h>

// DimeNet-like GNN, f32 in/out (flag=1 confirmed round 2/3/5).
// Round 6: bucket-per-wave segment sums (no atomics, no per-layer zeroing,
// cursor array from counting sort reused as bucket ends), batch-4 prefetch
// pipelines to break the order->t->k->Hh dependent-load chain, Hs+Ad fused
// into one dual-job GEMM launch, merged scans. Unsorted fallback retained.

#define N_NODES 16000
#define N_EDGES 256000
#define N_TRI   640000
#define N_B     128
#define OUT_DIM 32
#define L_LAYERS 3

typedef __hip_bfloat16 bf16;
typedef short s8v __attribute__((ext_vector_type(8)));
typedef float f4v __attribute__((ext_vector_type(4)));

__device__ __forceinline__ float ldx(const void* p, size_t i, int f) {
    if (f) return ((const float*)p)[i];
    return __bfloat162float(((const bf16*)p)[i]);
}

// ---- bf16 split helpers (bit-level, RNE) ----
__device__ __forceinline__ unsigned short f2bf_rne(float x) {
    unsigned int u = __float_as_uint(x);
    unsigned int r = (u + 0x7FFFu + ((u >> 16) & 1u)) >> 16;
    return (unsigned short)r;
}
__device__ __forceinline__ float bf2f(unsigned short b) {
    return __uint_as_float(((unsigned int)b) << 16);
}
__device__ __forceinline__ void split2(float a, unsigned short& h, unsigned short& l) {
    h = f2bf_rne(a);
    l = f2bf_rne(a - bf2f(h));
}
__device__ __forceinline__ void make_afrag(const float* av, s8v& ah, s8v& al) {
    #pragma unroll
    for (int j = 0; j < 8; j++) {
        unsigned short h, l; split2(av[j], h, l);
        ah[j] = (short)h; al[j] = (short)l;
    }
}

#define MFMA_STEP(ks, ah, al)                                                    \
    {                                                                            \
        _Pragma("unroll")                                                        \
        for (int nt = 0; nt < 4; nt++) {                                         \
            s8v bh = *(const s8v*)&sBhi[((ks) * 4 + nt) * 512 + lane * 8];       \
            s8v bl = *(const s8v*)&sBlo[((ks) * 4 + nt) * 512 + lane * 8];       \
            acc[nt] = __builtin_amdgcn_mfma_f32_16x16x32_bf16(ah, bh, acc[nt], 0, 0, 0); \
            acc[nt] = __builtin_amdgcn_mfma_f32_16x16x32_bf16(al, bh, acc[nt], 0, 0, 0); \
            acc[nt] = __builtin_amdgcn_mfma_f32_16x16x32_bf16(ah, bl, acc[nt], 0, 0, 0); \
        }                                                                        \
    }

#define LOAD_A8(base, ks, av)                                                    \
    {                                                                            \
        const float4* p_ = (const float4*)((base) + (ks) * 32 + quad * 8);       \
        float4 x0_ = p_[0], x1_ = p_[1];                                         \
        av[0] = x0_.x; av[1] = x0_.y; av[2] = x0_.z; av[3] = x0_.w;              \
        av[4] = x1_.x; av[5] = x1_.y; av[6] = x1_.z; av[7] = x1_.w;              \
    }

// ---------------------------------------------------------------- misc
__global__ void k_probe(const void* __restrict__ rbf, int* __restrict__ flag) {
    if (threadIdx.x == 0 && blockIdx.x == 0) {
        const float* p = (const float*)rbf;
        int good = 0;
        for (int i = 0; i < 256; i++) {
            float v = fabsf(p[i]);
            if (v > 1e-4f && v < 100.0f) good++;
        }
        *flag = (good > 192) ? 1 : 0;
    }
}

__global__ void k_fill(void* __restrict__ out, const int* __restrict__ flag,
                       float val, int n) {
    int i = blockIdx.x * blockDim.x + threadIdx.x;
    if (i < n) {
        if (*flag) ((float*)out)[i] = val;
        else       ((bf16*)out)[i] = __float2bfloat16(val);
    }
}

__global__ void k_zero(float* __restrict__ p, int n) {
    int i = blockIdx.x * blockDim.x + threadIdx.x;
    int stride = gridDim.x * blockDim.x;
    for (; i < n; i += stride) p[i] = 0.0f;
}

__global__ void k_zeroi(int* __restrict__ p, int n) {
    int i = blockIdx.x * blockDim.x + threadIdx.x;
    int stride = gridDim.x * blockDim.x;
    for (; i < n; i += stride) p[i] = 0;
}

__global__ void k_hinit(const void* __restrict__ x, float* __restrict__ h,
                        const int* __restrict__ flag) {
    int f = *flag;
    int i = blockIdx.x * blockDim.x + threadIdx.x;
    if (i < N_NODES * 64) h[i] = ldx(x, i, f);
}

// ---------------------------------------------------------------- counting sort
__global__ void k_hist(const int* __restrict__ key, int n, int* __restrict__ cnt) {
    int i = blockIdx.x * blockDim.x + threadIdx.x;
    if (i < n) {
        unsigned k = (unsigned)key[i];
        if (k < N_NODES) atomicAdd(&cnt[k], 1);
    }
}

// exclusive prefix scan of N_NODES ints, in place; block 0 -> a, block 1 -> b.
__global__ __launch_bounds__(256) void k_scan2(int* __restrict__ a, int* __restrict__ b) {
    int* cnt = (blockIdx.x == 0) ? a : b;
    __shared__ int part[256];
    int tid = threadIdx.x;
    const int PER = (N_NODES + 255) / 256;  // 63
    int base = tid * PER;
    int s = 0;
    for (int i = 0; i < PER; i++) {
        int idx = base + i;
        if (idx < N_NODES) s += cnt[idx];
    }
    part[tid] = s;
    __syncthreads();
    for (int d = 1; d < 256; d <<= 1) {
        int v = (tid >= d) ? part[tid - d] : 0;
        __syncthreads();
        part[tid] += v;
        __syncthreads();
    }
    int run = (tid > 0) ? part[tid - 1] : 0;
    for (int i = 0; i < PER; i++) {
        int idx = base + i;
        if (idx < N_NODES) {
            int v = cnt[idx];
            cnt[idx] = run;
            run += v;
        }
    }
}

__global__ void k_scatter(const int* __restrict__ key, int n,
                          int* __restrict__ cursor, int* __restrict__ order) {
    int i = blockIdx.x * blockDim.x + threadIdx.x;
    if (i < n) {
        unsigned k = (unsigned)key[i];
        if (k < N_NODES) {
            int pos = atomicAdd(&cursor[k], 1);
            if ((unsigned)pos < (unsigned)n) order[pos] = i;
        }
    }
    // after this kernel, cursor[k] == end offset of bucket k
}

// ---------------------------------------------------------------- linear (MFMA) body
// out[n] = (relu?)(A1[n]@W[0:64] (+ A2[n]@W[64:128] if KS==4) + bias).
// Split-bf16 3-product. In-place safe: wave reads its 16 rows before storing.
template<int KS>
__device__ __forceinline__ void lin_body(
    const float* __restrict__ A1, const float* __restrict__ A2,
    const void* __restrict__ W, size_t offW,
    const void* __restrict__ bias, size_t offB, int do_relu, int f,
    float* __restrict__ out, int bid, int nblocks,
    unsigned short* sBhi, unsigned short* sBlo, float* sBias) {
    for (int idx = threadIdx.x; idx < KS * 2048; idx += 256) {
        int jj = idx & 7, ln = (idx >> 3) & 63, nt = (idx >> 9) & 3, ks = idx >> 11;
        int k = ks * 32 + (ln >> 4) * 8 + jj;
        int n = nt * 16 + (ln & 15);
        float w = ldx(W, offW + (size_t)k * 64 + n, f);
        unsigned short h_, l_; split2(w, h_, l_);
        sBhi[idx] = h_; sBlo[idx] = l_;
    }
    if (threadIdx.x < 64)
        sBias[threadIdx.x] = bias ? ldx(bias, offB + threadIdx.x, f) : 0.f;
    __syncthreads();
    int lane = threadIdx.x & 63;
    int quad = lane >> 4;
    int m = lane & 15;
    int wave = bid * 4 + (threadIdx.x >> 6);
    int nwaves = nblocks * 4;
    const int NT = N_NODES / 16;
    for (int tile = wave; tile < NT; tile += nwaves) {
        int row = tile * 16 + m;
        f4v acc[4];
        #pragma unroll
        for (int nt = 0; nt < 4; nt++) {
            float b = sBias[nt * 16 + m];
            acc[nt] = (f4v){b, b, b, b};
        }
        const float* r1 = A1 + (size_t)row * 64;
        float av[8]; s8v ah, al;
        LOAD_A8(r1, 0, av) make_afrag(av, ah, al); MFMA_STEP(0, ah, al)
        LOAD_A8(r1, 1, av) make_afrag(av, ah, al); MFMA_STEP(1, ah, al)
        if (KS == 4) {
            const float* r2 = A2 + (size_t)row * 64;
            LOAD_A8(r2, 0, av) make_afrag(av, ah, al); MFMA_STEP(2, ah, al)
            LOAD_A8(r2, 1, av) make_afrag(av, ah, al); MFMA_STEP(3, ah, al)
        }
        #pragma unroll
        for (int r = 0; r < 4; r++) {
            float* dp = out + (size_t)(tile * 16 + quad * 4 + r) * 64 + m;
            #pragma unroll
            for (int nt = 0; nt < 4; nt++) {
                float v = acc[nt][r];
                dp[nt * 16] = do_relu ? fmaxf(v, 0.f) : v;
            }
        }
    }
}

template<int KS>
__global__ __launch_bounds__(256) void k_lin(
    const float* __restrict__ A1, const float* __restrict__ A2,
    const void* __restrict__ W, size_t offW,
    const void* __restrict__ bias, size_t offB, int do_relu,
    const int* __restrict__ flag, float* __restrict__ out) {
    __shared__ unsigned short sBhi[KS * 2048], sBlo[KS * 2048];
    __shared__ float sBias[64];
    lin_body<KS>(A1, A2, W, offW, bias, offB, do_relu, *flag, out,
                 blockIdx.x, gridDim.x, sBhi, sBlo, sBias);
}

// dual: blocks [0,half) do job0 (Hs = h@W+b -> out0), rest job1 (Ad = A1'@W' -> out1)
__global__ __launch_bounds__(256) void k_lin_dual(
    const float* __restrict__ A0, const void* __restrict__ W0, size_t offW0,
    const void* __restrict__ bias0, size_t offB0, float* __restrict__ out0,
    const float* __restrict__ A1v, const void* __restrict__ W1v, size_t offW1,
    float* __restrict__ out1, int half, const int* __restrict__ flag) {
    __shared__ unsigned short sBhi[2 * 2048], sBlo[2 * 2048];
    __shared__ float sBias[64];
    int f = *flag;
    if ((int)blockIdx.x < half)
        lin_body<2>(A0, nullptr, W0, offW0, bias0, offB0, 0, f, out0,
                    blockIdx.x, half, sBhi, sBlo, sBias);
    else
        lin_body<2>(A1v, nullptr, W1v, offW1, nullptr, 0, 0, f, out1,
                    blockIdx.x - half, gridDim.x - half, sBhi, sBlo, sBias);
}

// ---------------------------------------------------------------- triplet segment sum (sorted)
// wave per node j: agg_e[j] = sum over bucket relu(Hh[k_t] + rbf[j]@W1r + cbf[t]@W1c).
// Plain store (no atomics, no pre-zeroing). Batch-4 prefetch breaks the chain.
__global__ __launch_bounds__(256) void k_tri_seg(
    const int* __restrict__ order, const int* __restrict__ ends,
    const int* __restrict__ k_idx,
    const float* __restrict__ Hh, const void* __restrict__ rbf,
    const void* __restrict__ cbf, const void* __restrict__ W1, size_t offW,
    const int* __restrict__ flag, float* __restrict__ agg_e) {
    int f = *flag;
    int c = threadIdx.x & 63;
    float wr[6], wc[6];
    #pragma unroll
    for (int q = 0; q < 6; q++) {
        wr[q] = ldx(W1, offW + (size_t)(64 + q) * 64 + c, f);
        wc[q] = ldx(W1, offW + (size_t)(70 + q) * 64 + c, f);
    }
    int j = blockIdx.x * 4 + (threadIdx.x >> 6);
    if (j >= N_NODES) return;
    int p0 = (j == 0) ? 0 : ends[j - 1];
    int p1 = ends[j];
    if (p0 < 0) p0 = 0; if (p0 > N_TRI) p0 = N_TRI;
    if (p1 < p0) p1 = p0; if (p1 > N_TRI) p1 = N_TRI;
    float rb = 0.f;
    #pragma unroll
    for (int q = 0; q < 6; q++)
        rb += ldx(rbf, (size_t)j * 6 + q, f) * wr[q];
    float s = 0.f;
    for (int p = p0; p < p1; p += 4) {
        int tt[4], kk[4];
        float cb[4][6], hv[4];
        #pragma unroll
        for (int i = 0; i < 4; i++) {
            int pp = p + i;
            int t = (pp < p1) ? order[pp] : -1;
            if ((unsigned)t >= N_TRI) t = -1;
            tt[i] = t;
        }
        #pragma unroll
        for (int i = 0; i < 4; i++) {
            int t = tt[i];
            int k = (t >= 0) ? k_idx[t] : 0;
            if ((unsigned)k >= N_NODES) k = 0;
            kk[i] = k;
            #pragma unroll
            for (int q = 0; q < 6; q++)
                cb[i][q] = (t >= 0) ? ldx(cbf, (size_t)t * 6 + q, f) : 0.f;
        }
        #pragma unroll
        for (int i = 0; i < 4; i++)
            hv[i] = Hh[(size_t)kk[i] * 64 + c];
        #pragma unroll
        for (int i = 0; i < 4; i++) {
            if (tt[i] < 0) continue;
            float v = hv[i] + rb;
            #pragma unroll
            for (int q = 0; q < 6; q++)
                v += cb[i][q] * wc[q];
            s += fmaxf(v, 0.f);
        }
    }
    agg_e[(size_t)j * 64 + c] = s;
}

// ---------------------------------------------------------------- edge segment sum (sorted)
// wave per node d: aggr[d] = sum over bucket relu(Hs[src_e] + Ad[d]). Plain store.
__global__ __launch_bounds__(256) void k_edge_seg(
    const int* __restrict__ order, const int* __restrict__ ends,
    const int* __restrict__ edge_index,
    const float* __restrict__ Hs, const float* __restrict__ Ad,
    float* __restrict__ aggr) {
    int c = threadIdx.x & 63;
    int d = blockIdx.x * 4 + (threadIdx.x >> 6);
    if (d >= N_NODES) return;
    int p0 = (d == 0) ? 0 : ends[d - 1];
    int p1 = ends[d];
    if (p0 < 0) p0 = 0; if (p0 > N_EDGES) p0 = N_EDGES;
    if (p1 < p0) p1 = p0; if (p1 > N_EDGES) p1 = N_EDGES;
    float ad = Ad[(size_t)d * 64 + c];
    float s = 0.f;
    for (int p = p0; p < p1; p += 4) {
        int ee[4], ss[4];
        float hv[4];
        #pragma unroll
        for (int i = 0; i < 4; i++) {
            int pp = p + i;
            int e = (pp < p1) ? order[pp] : -1;
            if ((unsigned)e >= N_EDGES) e = -1;
            ee[i] = e;
        }
        #pragma unroll
        for (int i = 0; i < 4; i++) {
            int src = (ee[i] >= 0) ? edge_index[ee[i]] : 0;
            if ((unsigned)src >= N_NODES) src = 0;
            ss[i] = src;
        }
        #pragma unroll
        for (int i = 0; i < 4; i++)
            hv[i] = Hs[(size_t)ss[i] * 64 + c];
        #pragma unroll
        for (int i = 0; i < 4; i++) {
            if (ee[i] < 0) continue;
            s += fmaxf(hv[i] + ad, 0.f);
        }
    }
    aggr[(size_t)d * 64 + c] = s;
}

// ---------------------------------------------------------------- unsorted fallbacks
__global__ __launch_bounds__(256) void k_tri_sum_u(
    const int* __restrict__ j_idx, const int* __restrict__ k_idx,
    const float* __restrict__ Hh, const void* __restrict__ rbf,
    const void* __restrict__ cbf, const void* __restrict__ W1, size_t offW,
    const int* __restrict__ flag, float* __restrict__ agg_e) {
    int f = *flag;
    int c = threadIdx.x & 63;
    float wr[6], wc[6];
    #pragma unroll
    for (int q = 0; q < 6; q++) {
        wr[q] = ldx(W1, offW + (size_t)(64 + q) * 64 + c, f);
        wc[q] = ldx(W1, offW + (size_t)(70 + q) * 64 + c, f);
    }
    int wave = blockIdx.x * 4 + (threadIdx.x >> 6);
    int nw = gridDim.x * 4;
    for (int t = wave; t < N_TRI; t += nw) {
        unsigned j = (unsigned)j_idx[t];
        if (j >= N_NODES) continue;
        unsigned k = (unsigned)k_idx[t]; if (k >= N_NODES) k = 0;
        float v = Hh[(size_t)k * 64 + c];
        #pragma unroll
        for (int q = 0; q < 6; q++)
            v += ldx(rbf, (size_t)j * 6 + q, f) * wr[q]
               + ldx(cbf, (size_t)t * 6 + q, f) * wc[q];
        atomicAdd(&agg_e[(size_t)j * 64 + c], fmaxf(v, 0.f));
    }
}

__global__ __launch_bounds__(256) void k_edge_sum_u(
    const int* __restrict__ edge_index,
    const float* __restrict__ Hs, const float* __restrict__ Ad,
    float* __restrict__ aggr) {
    int c = threadIdx.x & 63;
    int wave = blockIdx.x * 4 + (threadIdx.x >> 6);
    int nw = gridDim.x * 4;
    for (int e = wave; e < N_EDGES; e += nw) {
        unsigned src = (unsigned)edge_index[e];
        unsigned dst = (unsigned)edge_index[N_EDGES + e];
        if (dst >= N_NODES) continue;
        if (src >= N_NODES) src = 0;
        float v = fmaxf(Hs[(size_t)src * 64 + c] + Ad[(size_t)dst * 64 + c], 0.f);
        atomicAdd(&aggr[(size_t)dst * 64 + c], v);
    }
}

// ---------------------------------------------------------------- global mean pool
__global__ void k_pool(const float* __restrict__ h, const int* __restrict__ batch,
                       float* __restrict__ pooled, float* __restrict__ cnt) {
    int lane = threadIdx.x & 63;
    int gwave = blockIdx.x * (blockDim.x >> 6) + (threadIdx.x >> 6);
    int nwaves = gridDim.x * (blockDim.x >> 6);
    for (int n = gwave; n < N_NODES; n += nwaves) {
        unsigned b = (unsigned)batch[n];
        if (b >= N_B) continue;
        atomicAdd(&pooled[b * 64 + lane], h[n * 64 + lane]);
        if (lane == 0) atomicAdd(&cnt[b], 1.0f);
    }
}

// ---------------------------------------------------------------- output head
__global__ void k_head(const float* __restrict__ pooled, const float* __restrict__ cnt,
                       const void* __restrict__ Wo1, const void* __restrict__ bo1,
                       const void* __restrict__ Wo2, const void* __restrict__ bo2,
                       const int* __restrict__ flag, void* __restrict__ out) {
    int f = *flag;
    int lane = threadIdx.x & 63;
    int b = blockIdx.x * (blockDim.x >> 6) + (threadIdx.x >> 6);
    if (b >= N_B) return;
    float c = cnt[b];
    float p = fmaxf(pooled[b * 64 + lane] / fmaxf(c, 1.0f), 0.f);
    float acc = ldx(bo1, lane, f);
    #pragma unroll
    for (int kk = 0; kk < 64; kk++)
        acc += __shfl(p, kk) * ldx(Wo1, kk * 64 + lane, f);
    float t1 = fmaxf(acc, 0.f);
    float acc2 = (lane < OUT_DIM) ? ldx(bo2, lane, f) : 0.f;
    #pragma unroll
    for (int kk = 0; kk < 64; kk++) {
        float w = (lane < OUT_DIM) ? ldx(Wo2, kk * OUT_DIM + lane, f) : 0.f;
        acc2 += __shfl(t1, kk) * w;
    }
    if (lane < OUT_DIM) {
        if (f) ((float*)out)[b * OUT_DIM + lane] = acc2;
        else   ((bf16*)out)[b * OUT_DIM + lane] = __float2bfloat16(acc2);
    }
}

extern "C" void kernel_launch(void* const* d_in, const int* in_sizes, int n_in,
                              void* d_out, int out_size, void* d_ws, size_t ws_size,
                              hipStream_t stream) {
    const int expect[19] = {
        N_NODES * 64, N_EDGES * 6, N_TRI * 6,
        L_LAYERS * 76 * 64, L_LAYERS * 64,
        L_LAYERS * 128 * 64, L_LAYERS * 64,
        L_LAYERS * 128 * 64, L_LAYERS * 64,
        L_LAYERS * 64 * 64, L_LAYERS * 64,
        64 * 64, 64, 64 * OUT_DIM, OUT_DIM,
        2 * N_EDGES, N_TRI, N_TRI, N_NODES
    };

    char* ws = (char*)d_ws;
    float* h      = (float*)(ws + 0);           // 4,096,000
    float* agg_e  = (float*)(ws + 4096000);     // 4,096,000 (agg_e -> Ad in place)
    float* aggr   = (float*)(ws + 8192000);     // 4,096,000
    float* X      = (float*)(ws + 12288000);    // 4,096,000 (Hh -> Hs -> Zn)
    float* pooled = (float*)(ws + 16384000);    // 32,768
    float* cnt    = (float*)(ws + 16416768);    // 512
    int*   flag   = (int*)(ws + 16417280);      // 256
    int*   tri_o  = (int*)(ws + 16417536);      // 2,560,000
    int*   edge_o = (int*)(ws + 18977536);      // 1,024,000
    int*   cur_t  = (int*)(ws + 20001536);      // 64,000  (-> tri bucket ends)
    int*   cur_e  = (int*)(ws + 20065536);      // 64,000  (-> edge bucket ends)
    const size_t FULL_NEED = 20129536u;
    const size_t BASE_NEED = 16417540u;

    const int out_n = N_B * OUT_DIM;

    int perm[19];
    bool used[64];
    for (int i = 0; i < 64; i++) used[i] = false;
    int fail_slot = -1;
    for (int i = 0; i < 19; i++) {
        perm[i] = -1;
        for (int jj = 0; jj < n_in && jj < 64; jj++) {
            if (!used[jj] && in_sizes[jj] == expect[i]) { used[jj] = true; perm[i] = jj; break; }
        }
        if (perm[i] < 0 && fail_slot < 0) fail_slot = i;
    }

    if (n_in < 19 || fail_slot >= 0 || ws_size < BASE_NEED) {
        float code = (ws_size < BASE_NEED) ? 40000.0f
                   : (n_in < 19)           ? 50000.0f
                   : 20000.0f + 1000.0f * (float)fail_slot;
        k_probe<<<1, 64, 0, stream>>>(d_in[0], flag);
        k_fill<<<(out_n + 255) / 256, 256, 0, stream>>>(d_out, flag, code, out_n);
        return;
    }

    const void* x    = d_in[perm[0]];
    const void* rbf  = d_in[perm[1]];
    const void* cbf  = d_in[perm[2]];
    const void* W1   = d_in[perm[3]];
    const void* b1   = d_in[perm[4]];
    const void* W2   = d_in[perm[5]];
    const void* b2   = d_in[perm[6]];
    const void* Wn1  = d_in[perm[7]];
    const void* bn1  = d_in[perm[8]];
    const void* Wn2  = d_in[perm[9]];
    const void* bn2  = d_in[perm[10]];
    const void* Wo1  = d_in[perm[11]];
    const void* bo1  = d_in[perm[12]];
    const void* Wo2  = d_in[perm[13]];
    const void* bo2  = d_in[perm[14]];
    const int* edge_index = (const int*)d_in[perm[15]];
    const int* k_idx = (const int*)d_in[perm[16]];
    const int* j_idx = (const int*)d_in[perm[17]];
    const int* batch = (const int*)d_in[perm[18]];

    const int sorted = (ws_size >= FULL_NEED) ? 1 : 0;

    k_probe<<<1, 64, 0, stream>>>(rbf, flag);
    k_zero<<<64, 256, 0, stream>>>(pooled, N_B * 64 + N_B);
    k_hinit<<<(N_NODES * 64 + 255) / 256, 256, 0, stream>>>(x, h, flag);

    if (sorted) {
        k_zeroi<<<125, 256, 0, stream>>>(cur_t, 2 * N_NODES);  // cur_t+cur_e contiguous
        k_hist<<<(N_TRI + 255) / 256, 256, 0, stream>>>(j_idx, N_TRI, cur_t);
        k_hist<<<(N_EDGES + 255) / 256, 256, 0, stream>>>(edge_index + N_EDGES, N_EDGES, cur_e);
        k_scan2<<<2, 256, 0, stream>>>(cur_t, cur_e);
        k_scatter<<<(N_TRI + 255) / 256, 256, 0, stream>>>(j_idx, N_TRI, cur_t, tri_o);
        k_scatter<<<(N_EDGES + 255) / 256, 256, 0, stream>>>(edge_index + N_EDGES, N_EDGES, cur_e, edge_o);
        // cur_t / cur_e now hold bucket END offsets (stable across layers)
    }

    const int SEG_GRID = (N_NODES + 3) / 4;  // 4000 blocks, wave per node
    for (int l = 0; l < L_LAYERS; l++) {
        size_t offW1  = (size_t)l * 76 * 64;
        size_t offW2  = (size_t)l * 128 * 64;
        size_t offWn2 = (size_t)l * 64 * 64;
        size_t offB   = (size_t)l * 64;
        // Hh = h @ W1[0:64] + b1
        k_lin<2><<<250, 256, 0, stream>>>(h, nullptr, W1, offW1, b1, offB, 0, flag, X);
        // agg_e = segment_sum_j relu(Hh[k] + rbf[j]@W1r + cbf[t]@W1c)
        if (sorted) {
            k_tri_seg<<<SEG_GRID, 256, 0, stream>>>(tri_o, cur_t, k_idx, X, rbf, cbf,
                                                    W1, offW1, flag, agg_e);
        } else {
            k_zero<<<2048, 256, 0, stream>>>(agg_e, 2 * N_NODES * 64);
            k_tri_sum_u<<<2048, 256, 0, stream>>>(j_idx, k_idx, X, rbf, cbf,
                                                  W1, offW1, flag, agg_e);
        }
        // Hs = h @ W2[0:64] + b2 -> X ; Ad = agg_e @ W2[64:128] -> agg_e (in place)
        k_lin_dual<<<500, 256, 0, stream>>>(h, W2, offW2, b2, offB, X,
                                            agg_e, W2, offW2 + 64 * 64, agg_e,
                                            250, flag);
        // aggr = segment_sum_dst relu(Hs[src] + Ad[dst])
        if (sorted)
            k_edge_seg<<<SEG_GRID, 256, 0, stream>>>(edge_o, cur_e, edge_index,
                                                     X, agg_e, aggr);
        else
            k_edge_sum_u<<<1024, 256, 0, stream>>>(edge_index, X, agg_e, aggr);
        // Zn = relu([h | aggr] @ Wn1 + bn1)
        k_lin<4><<<250, 256, 0, stream>>>(h, aggr, Wn1, offW2, bn1, offB, 1, flag, X);
        // h = Zn @ Wn2 + bn2
        k_lin<2><<<250, 256, 0, stream>>>(X, nullptr, Wn2, offWn2, bn2, offB, 0, flag, h);
    }
    k_pool<<<512, 256, 0, stream>>>(h, batch, pooled, cnt);
    k_head<<<32, 256, 0, stream>>>(pooled, cnt, Wo1, bo1, Wo2, bo2, flag, d_out);
}

// Round 8
// 421.457 us; speedup vs baseline: 2.2348x; 1.1391x over previous
//
#include <hip/hip_runtime.h>
#include <hip/hip_bf16.h>

// DimeNet-like GNN, f32 in/out (flag=1 confirmed rounds 2-6).
// Round 7: k_pool rewritten as binary-search segment sum over the sorted
// batch array (78us of same-address atomic contention -> ~3us, no setup);
// batch-8 prefetch in tri/edge segment sums (was 4) to deepen the
// independent L2 chains; dead k_zero(pooled) removed.

#define N_NODES 16000
#define N_EDGES 256000
#define N_TRI   640000
#define N_B     128
#define OUT_DIM 32
#define L_LAYERS 3

typedef __hip_bfloat16 bf16;
typedef short s8v __attribute__((ext_vector_type(8)));
typedef float f4v __attribute__((ext_vector_type(4)));

__device__ __forceinline__ float ldx(const void* p, size_t i, int f) {
    if (f) return ((const float*)p)[i];
    return __bfloat162float(((const bf16*)p)[i]);
}

// ---- bf16 split helpers (bit-level, RNE) ----
__device__ __forceinline__ unsigned short f2bf_rne(float x) {
    unsigned int u = __float_as_uint(x);
    unsigned int r = (u + 0x7FFFu + ((u >> 16) & 1u)) >> 16;
    return (unsigned short)r;
}
__device__ __forceinline__ float bf2f(unsigned short b) {
    return __uint_as_float(((unsigned int)b) << 16);
}
__device__ __forceinline__ void split2(float a, unsigned short& h, unsigned short& l) {
    h = f2bf_rne(a);
    l = f2bf_rne(a - bf2f(h));
}
__device__ __forceinline__ void make_afrag(const float* av, s8v& ah, s8v& al) {
    #pragma unroll
    for (int j = 0; j < 8; j++) {
        unsigned short h, l; split2(av[j], h, l);
        ah[j] = (short)h; al[j] = (short)l;
    }
}

#define MFMA_STEP(ks, ah, al)                                                    \
    {                                                                            \
        _Pragma("unroll")                                                        \
        for (int nt = 0; nt < 4; nt++) {                                         \
            s8v bh = *(const s8v*)&sBhi[((ks) * 4 + nt) * 512 + lane * 8];       \
            s8v bl = *(const s8v*)&sBlo[((ks) * 4 + nt) * 512 + lane * 8];       \
            acc[nt] = __builtin_amdgcn_mfma_f32_16x16x32_bf16(ah, bh, acc[nt], 0, 0, 0); \
            acc[nt] = __builtin_amdgcn_mfma_f32_16x16x32_bf16(al, bh, acc[nt], 0, 0, 0); \
            acc[nt] = __builtin_amdgcn_mfma_f32_16x16x32_bf16(ah, bl, acc[nt], 0, 0, 0); \
        }                                                                        \
    }

#define LOAD_A8(base, ks, av)                                                    \
    {                                                                            \
        const float4* p_ = (const float4*)((base) + (ks) * 32 + quad * 8);       \
        float4 x0_ = p_[0], x1_ = p_[1];                                         \
        av[0] = x0_.x; av[1] = x0_.y; av[2] = x0_.z; av[3] = x0_.w;              \
        av[4] = x1_.x; av[5] = x1_.y; av[6] = x1_.z; av[7] = x1_.w;              \
    }

// ---------------------------------------------------------------- misc
__global__ void k_probe(const void* __restrict__ rbf, int* __restrict__ flag) {
    if (threadIdx.x == 0 && blockIdx.x == 0) {
        const float* p = (const float*)rbf;
        int good = 0;
        for (int i = 0; i < 256; i++) {
            float v = fabsf(p[i]);
            if (v > 1e-4f && v < 100.0f) good++;
        }
        *flag = (good > 192) ? 1 : 0;
    }
}

__global__ void k_fill(void* __restrict__ out, const int* __restrict__ flag,
                       float val, int n) {
    int i = blockIdx.x * blockDim.x + threadIdx.x;
    if (i < n) {
        if (*flag) ((float*)out)[i] = val;
        else       ((bf16*)out)[i] = __float2bfloat16(val);
    }
}

__global__ void k_zero(float* __restrict__ p, int n) {
    int i = blockIdx.x * blockDim.x + threadIdx.x;
    int stride = gridDim.x * blockDim.x;
    for (; i < n; i += stride) p[i] = 0.0f;
}

__global__ void k_zeroi(int* __restrict__ p, int n) {
    int i = blockIdx.x * blockDim.x + threadIdx.x;
    int stride = gridDim.x * blockDim.x;
    for (; i < n; i += stride) p[i] = 0;
}

__global__ void k_hinit(const void* __restrict__ x, float* __restrict__ h,
                        const int* __restrict__ flag) {
    int f = *flag;
    int i = blockIdx.x * blockDim.x + threadIdx.x;
    if (i < N_NODES * 64) h[i] = ldx(x, i, f);
}

// ---------------------------------------------------------------- counting sort
__global__ void k_hist(const int* __restrict__ key, int n, int* __restrict__ cnt) {
    int i = blockIdx.x * blockDim.x + threadIdx.x;
    if (i < n) {
        unsigned k = (unsigned)key[i];
        if (k < N_NODES) atomicAdd(&cnt[k], 1);
    }
}

// exclusive prefix scan of N_NODES ints, in place; block 0 -> a, block 1 -> b.
__global__ __launch_bounds__(256) void k_scan2(int* __restrict__ a, int* __restrict__ b) {
    int* cnt = (blockIdx.x == 0) ? a : b;
    __shared__ int part[256];
    int tid = threadIdx.x;
    const int PER = (N_NODES + 255) / 256;  // 63
    int base = tid * PER;
    int s = 0;
    for (int i = 0; i < PER; i++) {
        int idx = base + i;
        if (idx < N_NODES) s += cnt[idx];
    }
    part[tid] = s;
    __syncthreads();
    for (int d = 1; d < 256; d <<= 1) {
        int v = (tid >= d) ? part[tid - d] : 0;
        __syncthreads();
        part[tid] += v;
        __syncthreads();
    }
    int run = (tid > 0) ? part[tid - 1] : 0;
    for (int i = 0; i < PER; i++) {
        int idx = base + i;
        if (idx < N_NODES) {
            int v = cnt[idx];
            cnt[idx] = run;
            run += v;
        }
    }
}

__global__ void k_scatter(const int* __restrict__ key, int n,
                          int* __restrict__ cursor, int* __restrict__ order) {
    int i = blockIdx.x * blockDim.x + threadIdx.x;
    if (i < n) {
        unsigned k = (unsigned)key[i];
        if (k < N_NODES) {
            int pos = atomicAdd(&cursor[k], 1);
            if ((unsigned)pos < (unsigned)n) order[pos] = i;
        }
    }
    // after this kernel, cursor[k] == end offset of bucket k
}

// ---------------------------------------------------------------- linear (MFMA) body
template<int KS>
__device__ __forceinline__ void lin_body(
    const float* __restrict__ A1, const float* __restrict__ A2,
    const void* __restrict__ W, size_t offW,
    const void* __restrict__ bias, size_t offB, int do_relu, int f,
    float* __restrict__ out, int bid, int nblocks,
    unsigned short* sBhi, unsigned short* sBlo, float* sBias) {
    for (int idx = threadIdx.x; idx < KS * 2048; idx += 256) {
        int jj = idx & 7, ln = (idx >> 3) & 63, nt = (idx >> 9) & 3, ks = idx >> 11;
        int k = ks * 32 + (ln >> 4) * 8 + jj;
        int n = nt * 16 + (ln & 15);
        float w = ldx(W, offW + (size_t)k * 64 + n, f);
        unsigned short h_, l_; split2(w, h_, l_);
        sBhi[idx] = h_; sBlo[idx] = l_;
    }
    if (threadIdx.x < 64)
        sBias[threadIdx.x] = bias ? ldx(bias, offB + threadIdx.x, f) : 0.f;
    __syncthreads();
    int lane = threadIdx.x & 63;
    int quad = lane >> 4;
    int m = lane & 15;
    int wave = bid * 4 + (threadIdx.x >> 6);
    int nwaves = nblocks * 4;
    const int NT = N_NODES / 16;
    for (int tile = wave; tile < NT; tile += nwaves) {
        int row = tile * 16 + m;
        f4v acc[4];
        #pragma unroll
        for (int nt = 0; nt < 4; nt++) {
            float b = sBias[nt * 16 + m];
            acc[nt] = (f4v){b, b, b, b};
        }
        const float* r1 = A1 + (size_t)row * 64;
        float av[8]; s8v ah, al;
        LOAD_A8(r1, 0, av) make_afrag(av, ah, al); MFMA_STEP(0, ah, al)
        LOAD_A8(r1, 1, av) make_afrag(av, ah, al); MFMA_STEP(1, ah, al)
        if (KS == 4) {
            const float* r2 = A2 + (size_t)row * 64;
            LOAD_A8(r2, 0, av) make_afrag(av, ah, al); MFMA_STEP(2, ah, al)
            LOAD_A8(r2, 1, av) make_afrag(av, ah, al); MFMA_STEP(3, ah, al)
        }
        #pragma unroll
        for (int r = 0; r < 4; r++) {
            float* dp = out + (size_t)(tile * 16 + quad * 4 + r) * 64 + m;
            #pragma unroll
            for (int nt = 0; nt < 4; nt++) {
                float v = acc[nt][r];
                dp[nt * 16] = do_relu ? fmaxf(v, 0.f) : v;
            }
        }
    }
}

template<int KS>
__global__ __launch_bounds__(256) void k_lin(
    const float* __restrict__ A1, const float* __restrict__ A2,
    const void* __restrict__ W, size_t offW,
    const void* __restrict__ bias, size_t offB, int do_relu,
    const int* __restrict__ flag, float* __restrict__ out) {
    __shared__ unsigned short sBhi[KS * 2048], sBlo[KS * 2048];
    __shared__ float sBias[64];
    lin_body<KS>(A1, A2, W, offW, bias, offB, do_relu, *flag, out,
                 blockIdx.x, gridDim.x, sBhi, sBlo, sBias);
}

// dual: blocks [0,half) do job0, rest job1
__global__ __launch_bounds__(256) void k_lin_dual(
    const float* __restrict__ A0, const void* __restrict__ W0, size_t offW0,
    const void* __restrict__ bias0, size_t offB0, float* __restrict__ out0,
    const float* __restrict__ A1v, const void* __restrict__ W1v, size_t offW1,
    float* __restrict__ out1, int half, const int* __restrict__ flag) {
    __shared__ unsigned short sBhi[2 * 2048], sBlo[2 * 2048];
    __shared__ float sBias[64];
    int f = *flag;
    if ((int)blockIdx.x < half)
        lin_body<2>(A0, nullptr, W0, offW0, bias0, offB0, 0, f, out0,
                    blockIdx.x, half, sBhi, sBlo, sBias);
    else
        lin_body<2>(A1v, nullptr, W1v, offW1, nullptr, 0, 0, f, out1,
                    blockIdx.x - half, gridDim.x - half, sBhi, sBlo, sBias);
}

// ---------------------------------------------------------------- triplet segment sum (sorted)
// wave per node j: agg_e[j] = sum over bucket relu(Hh[k_t] + rbf[j]@W1r + cbf[t]@W1c).
// Plain store, batch-8 prefetch.
__global__ __launch_bounds__(256) void k_tri_seg(
    const int* __restrict__ order, const int* __restrict__ ends,
    const int* __restrict__ k_idx,
    const float* __restrict__ Hh, const void* __restrict__ rbf,
    const void* __restrict__ cbf, const void* __restrict__ W1, size_t offW,
    const int* __restrict__ flag, float* __restrict__ agg_e) {
    int f = *flag;
    int c = threadIdx.x & 63;
    float wr[6], wc[6];
    #pragma unroll
    for (int q = 0; q < 6; q++) {
        wr[q] = ldx(W1, offW + (size_t)(64 + q) * 64 + c, f);
        wc[q] = ldx(W1, offW + (size_t)(70 + q) * 64 + c, f);
    }
    int j = blockIdx.x * 4 + (threadIdx.x >> 6);
    if (j >= N_NODES) return;
    int p0 = (j == 0) ? 0 : ends[j - 1];
    int p1 = ends[j];
    if (p0 < 0) p0 = 0; if (p0 > N_TRI) p0 = N_TRI;
    if (p1 < p0) p1 = p0; if (p1 > N_TRI) p1 = N_TRI;
    float rb = 0.f;
    #pragma unroll
    for (int q = 0; q < 6; q++)
        rb += ldx(rbf, (size_t)j * 6 + q, f) * wr[q];
    float s = 0.f;
    for (int p = p0; p < p1; p += 8) {
        int tt[8], kk[8];
        float cb[8][6], hv[8];
        #pragma unroll
        for (int i = 0; i < 8; i++) {
            int pp = p + i;
            int t = (pp < p1) ? order[pp] : -1;
            if ((unsigned)t >= N_TRI) t = -1;
            tt[i] = t;
        }
        #pragma unroll
        for (int i = 0; i < 8; i++) {
            int t = tt[i];
            int k = (t >= 0) ? k_idx[t] : 0;
            if ((unsigned)k >= N_NODES) k = 0;
            kk[i] = k;
            #pragma unroll
            for (int q = 0; q < 6; q++)
                cb[i][q] = (t >= 0) ? ldx(cbf, (size_t)t * 6 + q, f) : 0.f;
        }
        #pragma unroll
        for (int i = 0; i < 8; i++)
            hv[i] = Hh[(size_t)kk[i] * 64 + c];
        #pragma unroll
        for (int i = 0; i < 8; i++) {
            if (tt[i] < 0) continue;
            float v = hv[i] + rb;
            #pragma unroll
            for (int q = 0; q < 6; q++)
                v += cb[i][q] * wc[q];
            s += fmaxf(v, 0.f);
        }
    }
    agg_e[(size_t)j * 64 + c] = s;
}

// ---------------------------------------------------------------- edge segment sum (sorted)
__global__ __launch_bounds__(256) void k_edge_seg(
    const int* __restrict__ order, const int* __restrict__ ends,
    const int* __restrict__ edge_index,
    const float* __restrict__ Hs, const float* __restrict__ Ad,
    float* __restrict__ aggr) {
    int c = threadIdx.x & 63;
    int d = blockIdx.x * 4 + (threadIdx.x >> 6);
    if (d >= N_NODES) return;
    int p0 = (d == 0) ? 0 : ends[d - 1];
    int p1 = ends[d];
    if (p0 < 0) p0 = 0; if (p0 > N_EDGES) p0 = N_EDGES;
    if (p1 < p0) p1 = p0; if (p1 > N_EDGES) p1 = N_EDGES;
    float ad = Ad[(size_t)d * 64 + c];
    float s = 0.f;
    for (int p = p0; p < p1; p += 8) {
        int ee[8], ss[8];
        float hv[8];
        #pragma unroll
        for (int i = 0; i < 8; i++) {
            int pp = p + i;
            int e = (pp < p1) ? order[pp] : -1;
            if ((unsigned)e >= N_EDGES) e = -1;
            ee[i] = e;
        }
        #pragma unroll
        for (int i = 0; i < 8; i++) {
            int src = (ee[i] >= 0) ? edge_index[ee[i]] : 0;
            if ((unsigned)src >= N_NODES) src = 0;
            ss[i] = src;
        }
        #pragma unroll
        for (int i = 0; i < 8; i++)
            hv[i] = Hs[(size_t)ss[i] * 64 + c];
        #pragma unroll
        for (int i = 0; i < 8; i++) {
            if (ee[i] < 0) continue;
            s += fmaxf(hv[i] + ad, 0.f);
        }
    }
    aggr[(size_t)d * 64 + c] = s;
}

// ---------------------------------------------------------------- unsorted fallbacks
__global__ __launch_bounds__(256) void k_tri_sum_u(
    const int* __restrict__ j_idx, const int* __restrict__ k_idx,
    const float* __restrict__ Hh, const void* __restrict__ rbf,
    const void* __restrict__ cbf, const void* __restrict__ W1, size_t offW,
    const int* __restrict__ flag, float* __restrict__ agg_e) {
    int f = *flag;
    int c = threadIdx.x & 63;
    float wr[6], wc[6];
    #pragma unroll
    for (int q = 0; q < 6; q++) {
        wr[q] = ldx(W1, offW + (size_t)(64 + q) * 64 + c, f);
        wc[q] = ldx(W1, offW + (size_t)(70 + q) * 64 + c, f);
    }
    int wave = blockIdx.x * 4 + (threadIdx.x >> 6);
    int nw = gridDim.x * 4;
    for (int t = wave; t < N_TRI; t += nw) {
        unsigned j = (unsigned)j_idx[t];
        if (j >= N_NODES) continue;
        unsigned k = (unsigned)k_idx[t]; if (k >= N_NODES) k = 0;
        float v = Hh[(size_t)k * 64 + c];
        #pragma unroll
        for (int q = 0; q < 6; q++)
            v += ldx(rbf, (size_t)j * 6 + q, f) * wr[q]
               + ldx(cbf, (size_t)t * 6 + q, f) * wc[q];
        atomicAdd(&agg_e[(size_t)j * 64 + c], fmaxf(v, 0.f));
    }
}

__global__ __launch_bounds__(256) void k_edge_sum_u(
    const int* __restrict__ edge_index,
    const float* __restrict__ Hs, const float* __restrict__ Ad,
    float* __restrict__ aggr) {
    int c = threadIdx.x & 63;
    int wave = blockIdx.x * 4 + (threadIdx.x >> 6);
    int nw = gridDim.x * 4;
    for (int e = wave; e < N_EDGES; e += nw) {
        unsigned src = (unsigned)edge_index[e];
        unsigned dst = (unsigned)edge_index[N_EDGES + e];
        if (dst >= N_NODES) continue;
        if (src >= N_NODES) src = 0;
        float v = fmaxf(Hs[(size_t)src * 64 + c] + Ad[(size_t)dst * 64 + c], 0.f);
        atomicAdd(&aggr[(size_t)dst * 64 + c], v);
    }
}

// ---------------------------------------------------------------- pool (binary search over sorted batch)
// Block per graph b: rows [lower_bound(b), lower_bound(b+1)) are contiguous.
// Plain stores; no atomics; empty bucket -> 0.
__global__ __launch_bounds__(256) void k_pool_seg(
    const float* __restrict__ h, const int* __restrict__ batch,
    float* __restrict__ pooled, float* __restrict__ cnt) {
    __shared__ float red[4][64];
    int b = blockIdx.x;
    int lo = 0, hi = N_NODES;
    while (lo < hi) { int mid = (lo + hi) >> 1; if (batch[mid] < b) lo = mid + 1; else hi = mid; }
    int start = lo;
    hi = N_NODES;
    while (lo < hi) { int mid = (lo + hi) >> 1; if (batch[mid] < b + 1) lo = mid + 1; else hi = mid; }
    int end = lo;
    int lane = threadIdx.x & 63;
    int w = threadIdx.x >> 6;
    float s = 0.f;
    for (int n = start + w; n < end; n += 4)
        s += h[(size_t)n * 64 + lane];
    red[w][lane] = s;
    __syncthreads();
    if (w == 0) {
        float tot = red[0][lane] + red[1][lane] + red[2][lane] + red[3][lane];
        pooled[b * 64 + lane] = tot;
        if (lane == 0) cnt[b] = (float)(end - start);
    }
}

// ---------------------------------------------------------------- output head
__global__ void k_head(const float* __restrict__ pooled, const float* __restrict__ cnt,
                       const void* __restrict__ Wo1, const void* __restrict__ bo1,
                       const void* __restrict__ Wo2, const void* __restrict__ bo2,
                       const int* __restrict__ flag, void* __restrict__ out) {
    int f = *flag;
    int lane = threadIdx.x & 63;
    int b = blockIdx.x * (blockDim.x >> 6) + (threadIdx.x >> 6);
    if (b >= N_B) return;
    float c = cnt[b];
    float p = fmaxf(pooled[b * 64 + lane] / fmaxf(c, 1.0f), 0.f);
    float acc = ldx(bo1, lane, f);
    #pragma unroll
    for (int kk = 0; kk < 64; kk++)
        acc += __shfl(p, kk) * ldx(Wo1, kk * 64 + lane, f);
    float t1 = fmaxf(acc, 0.f);
    float acc2 = (lane < OUT_DIM) ? ldx(bo2, lane, f) : 0.f;
    #pragma unroll
    for (int kk = 0; kk < 64; kk++) {
        float w = (lane < OUT_DIM) ? ldx(Wo2, kk * OUT_DIM + lane, f) : 0.f;
        acc2 += __shfl(t1, kk) * w;
    }
    if (lane < OUT_DIM) {
        if (f) ((float*)out)[b * OUT_DIM + lane] = acc2;
        else   ((bf16*)out)[b * OUT_DIM + lane] = __float2bfloat16(acc2);
    }
}

extern "C" void kernel_launch(void* const* d_in, const int* in_sizes, int n_in,
                              void* d_out, int out_size, void* d_ws, size_t ws_size,
                              hipStream_t stream) {
    const int expect[19] = {
        N_NODES * 64, N_EDGES * 6, N_TRI * 6,
        L_LAYERS * 76 * 64, L_LAYERS * 64,
        L_LAYERS * 128 * 64, L_LAYERS * 64,
        L_LAYERS * 128 * 64, L_LAYERS * 64,
        L_LAYERS * 64 * 64, L_LAYERS * 64,
        64 * 64, 64, 64 * OUT_DIM, OUT_DIM,
        2 * N_EDGES, N_TRI, N_TRI, N_NODES
    };

    char* ws = (char*)d_ws;
    float* h      = (float*)(ws + 0);           // 4,096,000
    float* agg_e  = (float*)(ws + 4096000);     // 4,096,000 (agg_e -> Ad in place)
    float* aggr   = (float*)(ws + 8192000);     // 4,096,000
    float* X      = (float*)(ws + 12288000);    // 4,096,000 (Hh -> Hs -> Zn)
    float* pooled = (float*)(ws + 16384000);    // 32,768
    float* cnt    = (float*)(ws + 16416768);    // 512
    int*   flag   = (int*)(ws + 16417280);      // 256
    int*   tri_o  = (int*)(ws + 16417536);      // 2,560,000
    int*   edge_o = (int*)(ws + 18977536);      // 1,024,000
    int*   cur_t  = (int*)(ws + 20001536);      // 64,000  (-> tri bucket ends)
    int*   cur_e  = (int*)(ws + 20065536);      // 64,000  (-> edge bucket ends)
    const size_t FULL_NEED = 20129536u;
    const size_t BASE_NEED = 16417540u;

    const int out_n = N_B * OUT_DIM;

    int perm[19];
    bool used[64];
    for (int i = 0; i < 64; i++) used[i] = false;
    int fail_slot = -1;
    for (int i = 0; i < 19; i++) {
        perm[i] = -1;
        for (int jj = 0; jj < n_in && jj < 64; jj++) {
            if (!used[jj] && in_sizes[jj] == expect[i]) { used[jj] = true; perm[i] = jj; break; }
        }
        if (perm[i] < 0 && fail_slot < 0) fail_slot = i;
    }

    if (n_in < 19 || fail_slot >= 0 || ws_size < BASE_NEED) {
        float code = (ws_size < BASE_NEED) ? 40000.0f
                   : (n_in < 19)           ? 50000.0f
                   : 20000.0f + 1000.0f * (float)fail_slot;
        k_probe<<<1, 64, 0, stream>>>(d_in[0], flag);
        k_fill<<<(out_n + 255) / 256, 256, 0, stream>>>(d_out, flag, code, out_n);
        return;
    }

    const void* x    = d_in[perm[0]];
    const void* rbf  = d_in[perm[1]];
    const void* cbf  = d_in[perm[2]];
    const void* W1   = d_in[perm[3]];
    const void* b1   = d_in[perm[4]];
    const void* W2   = d_in[perm[5]];
    const void* b2   = d_in[perm[6]];
    const void* Wn1  = d_in[perm[7]];
    const void* bn1  = d_in[perm[8]];
    const void* Wn2  = d_in[perm[9]];
    const void* bn2  = d_in[perm[10]];
    const void* Wo1  = d_in[perm[11]];
    const void* bo1  = d_in[perm[12]];
    const void* Wo2  = d_in[perm[13]];
    const void* bo2  = d_in[perm[14]];
    const int* edge_index = (const int*)d_in[perm[15]];
    const int* k_idx = (const int*)d_in[perm[16]];
    const int* j_idx = (const int*)d_in[perm[17]];
    const int* batch = (const int*)d_in[perm[18]];

    const int sorted = (ws_size >= FULL_NEED) ? 1 : 0;

    k_probe<<<1, 64, 0, stream>>>(rbf, flag);
    k_hinit<<<(N_NODES * 64 + 255) / 256, 256, 0, stream>>>(x, h, flag);

    if (sorted) {
        k_zeroi<<<125, 256, 0, stream>>>(cur_t, 2 * N_NODES);  // cur_t+cur_e contiguous
        k_hist<<<(N_TRI + 255) / 256, 256, 0, stream>>>(j_idx, N_TRI, cur_t);
        k_hist<<<(N_EDGES + 255) / 256, 256, 0, stream>>>(edge_index + N_EDGES, N_EDGES, cur_e);
        k_scan2<<<2, 256, 0, stream>>>(cur_t, cur_e);
        k_scatter<<<(N_TRI + 255) / 256, 256, 0, stream>>>(j_idx, N_TRI, cur_t, tri_o);
        k_scatter<<<(N_EDGES + 255) / 256, 256, 0, stream>>>(edge_index + N_EDGES, N_EDGES, cur_e, edge_o);
        // cur_t / cur_e now hold bucket END offsets (stable across layers)
    }

    const int SEG_GRID = (N_NODES + 3) / 4;  // 4000 blocks, wave per node
    for (int l = 0; l < L_LAYERS; l++) {
        size_t offW1  = (size_t)l * 76 * 64;
        size_t offW2  = (size_t)l * 128 * 64;
        size_t offWn2 = (size_t)l * 64 * 64;
        size_t offB   = (size_t)l * 64;
        // Hh = h @ W1[0:64] + b1
        k_lin<2><<<250, 256, 0, stream>>>(h, nullptr, W1, offW1, b1, offB, 0, flag, X);
        // agg_e = segment_sum_j relu(Hh[k] + rbf[j]@W1r + cbf[t]@W1c)
        if (sorted) {
            k_tri_seg<<<SEG_GRID, 256, 0, stream>>>(tri_o, cur_t, k_idx, X, rbf, cbf,
                                                    W1, offW1, flag, agg_e);
        } else {
            k_zero<<<2048, 256, 0, stream>>>(agg_e, 2 * N_NODES * 64);
            k_tri_sum_u<<<2048, 256, 0, stream>>>(j_idx, k_idx, X, rbf, cbf,
                                                  W1, offW1, flag, agg_e);
        }
        // Hs = h @ W2[0:64] + b2 -> X ; Ad = agg_e @ W2[64:128] -> agg_e (in place)
        k_lin_dual<<<500, 256, 0, stream>>>(h, W2, offW2, b2, offB, X,
                                            agg_e, W2, offW2 + 64 * 64, agg_e,
                                            250, flag);
        // aggr = segment_sum_dst relu(Hs[src] + Ad[dst])
        if (sorted)
            k_edge_seg<<<SEG_GRID, 256, 0, stream>>>(edge_o, cur_e, edge_index,
                                                     X, agg_e, aggr);
        else
            k_edge_sum_u<<<1024, 256, 0, stream>>>(edge_index, X, agg_e, aggr);
        // Zn = relu([h | aggr] @ Wn1 + bn1)
        k_lin<4><<<250, 256, 0, stream>>>(h, aggr, Wn1, offW2, bn1, offB, 1, flag, X);
        // h = Zn @ Wn2 + bn2
        k_lin<2><<<250, 256, 0, stream>>>(X, nullptr, Wn2, offWn2, bn2, offB, 0, flag, h);
    }
    // pooled/cnt: plain-stored by k_pool_seg (batch is sorted -> contiguous ranges)
    k_pool_seg<<<N_B, 256, 0, stream>>>(h, batch, pooled, cnt);
    k_head<<<32, 256, 0, stream>>>(pooled, cnt, Wo1, bo1, Wo2, bo2, flag, d_out);
}